// Round 5
// baseline (594.791 us; speedup 1.0000x reference)
//
#include <hip/hip_runtime.h>
#include <stdint.h>

#define BATCH 64
#define NPTS 16384
#define MODEL_DIM 512
#define QL 2048
#define NROWS (BATCH * QL)

typedef unsigned short u16;
typedef __attribute__((ext_vector_type(8))) __bf16 bf16x8;
typedef __attribute__((ext_vector_type(4))) float f32x4;

// flags: [0..5] bf16? for boxes,scores,w1,b1,w2,b2; [6] labels-int64?; [7] valid-bool?
// out dtype = flags[0] (reference: outputs carry object_boxes.dtype)

__device__ __forceinline__ float loadf(const void* p, size_t i, uint32_t bf) {
  if (bf) {
    uint32_t u = ((const u16*)p)[i];
    return __uint_as_float(u << 16);
  }
  return ((const float*)p)[i];
}

__device__ __forceinline__ u16 f2bf_bits(float f) {
  __bf16 h = (__bf16)f;  // RNE
  return *(const u16*)&h;
}

__device__ __forceinline__ void storef(void* p, size_t i, float v, uint32_t bf) {
  if (bf) ((u16*)p)[i] = f2bf_bits(v);
  else ((float*)p)[i] = v;
}

__device__ __forceinline__ int load_label(const void* p, size_t i, uint32_t is64) {
  return is64 ? ((const int*)p)[2 * i] : ((const int*)p)[i];  // LE low word
}

__device__ __forceinline__ int load_valid(const void* p, size_t i, uint32_t isbool) {
  return isbool ? (int)((const unsigned char*)p)[i] : ((const int*)p)[i];
}

// ---------------------------------------------------------------------------
// Kernel 0: runtime dtype sniffer -> fl[8] in d_ws. One wave, ballot-parallel.
// ---------------------------------------------------------------------------
__global__ void sniff_kernel(const void* boxes, const void* scores,
                             const void* w1, const void* b1, const void* w2,
                             const void* b2, const void* labels,
                             const void* valid, uint32_t* fl) {
  const int lane = threadIdx.x;  // 64 threads, 1 block
  const void* bufs[6] = {boxes, scores, w1, b1, w2, b2};
#pragma unroll
  for (int t = 0; t < 6; ++t) {
    u16 v = ((const u16*)bufs[t])[lane];
    uint32_t e = (v >> 7) & 0xFFu;
    unsigned long long zb = __ballot(v == 0);
    unsigned long long cb = __ballot(e >= 100u && e <= 135u);
    if (lane == 0) {
      int z = __popcll(zb), c = __popcll(cb);
      // all-zero buffer (b1/b2): read as bf16 — values are 0 either way.
      fl[t] = (z >= 60) ? 1u : (c >= 56 ? 1u : 0u);
    }
  }
  uint32_t hw = (lane < 32) ? ((const uint32_t*)labels)[2 * lane + 1] : 0u;
  unsigned long long nz = __ballot(hw != 0u);
  uint32_t vv = ((const uint32_t*)valid)[lane];
  unsigned long long big = __ballot(vv > 1u);
  if (lane == 0) {
    fl[6] = (nz == 0ull) ? 1u : 0u;  // int64 iff high words all zero
    fl[7] = big ? 1u : 0u;           // bool-packed iff any non-{0,1} word
  }
}

// ---------------------------------------------------------------------------
// Kernel 1: w2 [K][N] -> w2f, MFMA-fragment-packed bf16:
// chunk c = ntile*16 + ks  (ntile = n/16, ks = k/32), 512 elems per chunk:
//   w2f[c*512 + lane*8 + e] = w2[ks*32 + (lane>>4)*8 + e][ntile*16 + (lane&15)]
// so GEMM2's A-fragment load becomes ONE fully-coalesced 1-KB dwordx4 per
// wave (was a 16-way scattered read at 2-KB stride).
// ---------------------------------------------------------------------------
__global__ void w2_pack_kernel(const void* __restrict__ w2,
                               u16* __restrict__ w2f,
                               const uint32_t* __restrict__ fl) {
  __shared__ u16 tile[32][33];  // [k'][n']
  const uint32_t bf = fl[4];
  const int ks = blockIdx.x;  // 0..15  (k block of 32)
  const int ng = blockIdx.y;  // 0..15  (n block of 32)
  const int tx = threadIdx.x, ty = threadIdx.y;  // (32, 8)
#pragma unroll
  for (int p = 0; p < 4; ++p) {
    int k = ks * 32 + ty + p * 8;
    int n = ng * 32 + tx;
    tile[ty + p * 8][tx] = f2bf_bits(loadf(w2, (size_t)k * MODEL_DIM + n, bf));
  }
  __syncthreads();
  const int t = ty * 32 + tx;        // 0..255
  const int ch = t >> 7;             // 0/1: which 16-wide n sub-tile
  const int w = t & 127;
  const int lane = w >> 1;           // 0..63
  const int e0 = (t & 1) * 4;        // elems e0..e0+3
  const int quad = lane >> 4, l16 = lane & 15;
  const int c = (ng * 2 + ch) * 16 + ks;
  ushort4 v;
  v.x = tile[quad * 8 + e0 + 0][ch * 16 + l16];
  v.y = tile[quad * 8 + e0 + 1][ch * 16 + l16];
  v.z = tile[quad * 8 + e0 + 2][ch * 16 + l16];
  v.w = tile[quad * 8 + e0 + 3][ch * 16 + l16];
  *(ushort4*)&w2f[(size_t)c * 512 + lane * 8 + e0] = v;
}

// ---------------------------------------------------------------------------
// Kernel 2: per-batch top-2048. 64-bit key = orderable(score)<<32 | ~idx
// (distinct keys, jax-stable tie-break). One 11-bit histogram pass +
// parallel suffix-scan finds the threshold bin; candidates (bin==T, expected
// ~8) compacted to a u16 list; remaining radix passes scan only that list,
// with early exit when bucket count == r. Worst case (>4096 ties) falls back
// to full-array scans (identical semantics). Bitonic sort for final order.
// ---------------------------------------------------------------------------
__global__ __launch_bounds__(1024) void topk_kernel(
    const void* __restrict__ scores, const void* __restrict__ valid,
    u16* __restrict__ idxbuf, const uint32_t* __restrict__ fl) {
  __shared__ uint32_t sk[NPTS];   // 64 KB orderable scores
  __shared__ uint64_t sel[QL];    // 16 KB; aliased as A/B u32[2048] work areas
  __shared__ uint32_t s_cnt, s_T, s_r, s_hi, s_ccnt;

  uint32_t* Aw = (uint32_t*)sel;       // [0..2048)
  uint32_t* Bw = Aw + 2048;            // [2048..4096)
  u16* cand = (u16*)Aw;                // 4096 entries, aliases Aw (free later)

  const uint32_t sbf = fl[1], vbool = fl[7];
  const int b = blockIdx.x;
  const int tid = threadIdx.x;

  // ---- load + orderable transform ----
  for (int i = tid; i < NPTS; i += 1024) {
    size_t g = (size_t)b * NPTS + i;
    float ms = load_valid(valid, g, vbool) ? loadf(scores, g, sbf) : -1e30f;
    uint32_t u = __float_as_uint(ms);
    sk[i] = (u & 0x80000000u) ? ~u : (u | 0x80000000u);
  }
  for (int i = tid; i < 2048; i += 1024) Aw[i] = 0u;
  __syncthreads();

  // ---- 11-bit histogram over top bits ----
  for (int i = tid; i < NPTS; i += 1024) atomicAdd(&Aw[sk[i] >> 21], 1u);
  __syncthreads();

  // ---- inclusive suffix scan (Hillis-Steele, 11 steps, ends in Bw) ----
  {
    uint32_t* src = Aw;
    uint32_t* dst = Bw;
    for (int d = 1; d < 2048; d <<= 1) {
      for (int i = tid; i < 2048; i += 1024)
        dst[i] = src[i] + ((i + d < 2048) ? src[i + d] : 0u);
      __syncthreads();
      uint32_t* tp = src; src = dst; dst = tp;
    }
    // src == Bw now holds S[v] = #elements with bin >= v (11 swaps)
    for (int v = tid; v < 2048; v += 1024) {
      uint32_t Sv = src[v];
      uint32_t Sn = (v < 2047) ? src[v + 1] : 0u;
      if (Sv >= QL && Sn < QL) { s_T = (uint32_t)v; s_r = QL - Sn; s_hi = Sn; }
    }
    __syncthreads();
  }
  const uint32_t T = s_T;
  const uint32_t r0 = s_r;
  const uint32_t histT = Bw[T] - s_hi;  // candidates in threshold bin

  // ---- compact candidates (bin == T) into u16 list if they fit ----
  const bool useCand = (histT <= 4096u);
  if (tid == 0) s_ccnt = 0u;
  __syncthreads();
  if (useCand) {
    for (int i = tid; i < NPTS; i += 1024)
      if ((sk[i] >> 21) == T) {
        uint32_t p = atomicAdd(&s_ccnt, 1u);
        cand[p] = (u16)i;
      }
  }
  __syncthreads();

  // ---- refine within bin T over remaining 53 key bits ----
  uint64_t V;
  if (histT == r0) {
    V = ((uint64_t)T) << 53;  // whole bin selected
  } else {
    uint64_t P = T;
    uint32_t r = r0;
    const int pos[7] = {45, 37, 29, 21, 13, 5, 0};
    const int wid[7] = {8, 8, 8, 8, 8, 8, 5};
    int done = 0;
    V = 0;
#pragma unroll 1
    for (int pp = 0; pp < 7; ++pp) {
      if (done) break;
      const int shift = pos[pp], db = wid[pp];
      const uint32_t nb = 1u << db;
      const uint32_t mask = nb - 1u;
      for (uint32_t i = tid; i < nb; i += 1024) Bw[i] = 0u;
      __syncthreads();
      const uint64_t Pc = P;
      const int hibits = shift + db;
      if (useCand) {
        const uint32_t cc = s_ccnt;
        for (uint32_t j = tid; j < cc; j += 1024) {
          int i = cand[j];
          uint64_t k = ((uint64_t)sk[i] << 32) | (uint32_t)(~i);
          if ((k >> hibits) == Pc)
            atomicAdd(&Bw[(uint32_t)(k >> shift) & mask], 1u);
        }
      } else {
        for (int i = tid; i < NPTS; i += 1024) {
          uint64_t k = ((uint64_t)sk[i] << 32) | (uint32_t)(~i);
          if ((k >> hibits) == Pc)
            atomicAdd(&Bw[(uint32_t)(k >> shift) & mask], 1u);
        }
      }
      __syncthreads();
      // suffix scan over nb bins (ping-pong within Bw[0..2nb))
      uint32_t* s0 = Bw;
      uint32_t* s1 = Bw + nb;
      for (uint32_t d = 1; d < nb; d <<= 1) {
        for (uint32_t i = tid; i < nb; i += 1024)
          s1[i] = s0[i] + ((i + d < nb) ? s0[i + d] : 0u);
        __syncthreads();
        uint32_t* tp = s0; s0 = s1; s1 = tp;
      }
      for (uint32_t v = tid; v < nb; v += 1024) {
        uint32_t Sv = s0[v];
        uint32_t Sn = (v < nb - 1) ? s0[v + 1] : 0u;
        if (Sv >= r && Sn < r) { s_T = v; s_hi = Sn; }
      }
      __syncthreads();
      const uint32_t chosen = s_T, hi2 = s_hi;
      const uint32_t histc = s0[chosen] - hi2;
      P = (P << db) | chosen;
      r = r - hi2;
      if (histc == r || shift == 0) {
        V = P << shift;
        done = 1;
      }
      __syncthreads();  // before next pass reuses Bw / s_T
    }
  }

  // ---- selection: exactly QL keys >= V (clobbers Aw/Bw == sel) ----
  if (tid == 0) s_cnt = 0u;
  __syncthreads();
  for (int i = tid; i < NPTS; i += 1024) {
    uint64_t k = ((uint64_t)sk[i] << 32) | (uint32_t)(~i);
    if (k >= V) {
      uint32_t p = atomicAdd(&s_cnt, 1u);
      if (p < QL) sel[p] = k;
    }
  }
  __syncthreads();

  // ---- bitonic sort descending ----
  for (int kk = 2; kk <= QL; kk <<= 1) {
    for (int j = kk >> 1; j > 0; j >>= 1) {
      for (int i = tid; i < QL; i += 1024) {
        int l = i ^ j;
        if (l > i) {
          uint64_t a = sel[i], c = sel[l];
          bool dir = ((i & kk) == 0);
          if ((a < c) == dir) { sel[i] = c; sel[l] = a; }
        }
      }
      __syncthreads();
    }
  }

  for (int q = tid; q < QL; q += 1024)
    idxbuf[b * QL + q] = (u16)((~(uint32_t)sel[q]) & (NPTS - 1));
}

// ---------------------------------------------------------------------------
// Kernel 3: fused MLP, 32 rows/block, 512 threads, 35.8 KB LDS ->
// 4 blocks/CU = 32 waves/CU (100% occupancy target).
// Gather 16 threads/row; GEMM1: half-block x 2-adjacent-cols over 16 rows,
// one-hot prefetched x4, vector (b128) rowdata reads, packed u32 writes into
// XOR-swizzled bf16 LDS; GEMM2: wave owns 64 n-cols, acc[2][4], bf16 MFMA
// swapped operands (acc reg walks n), fragment-packed w2f (coalesced 1-KB
// loads); b2 staged in LDS; f32x4/ushort4 bias+mask-fused stores.
// refs/scores outputs fused.
// ---------------------------------------------------------------------------
__global__ __launch_bounds__(512, 8) void mlp_kernel(
    const void* __restrict__ w1, const void* __restrict__ b1,
    const u16* __restrict__ w2f, const void* __restrict__ b2,
    const u16* __restrict__ idxbuf, const void* __restrict__ boxes,
    const void* __restrict__ scores, const void* __restrict__ labels,
    const void* __restrict__ valid, void* __restrict__ out,
    const uint32_t* __restrict__ fl) {
  __shared__ f32x4 rowf4[96];       // rowdata[32][12]  (1.5 KB)
  __shared__ float b2s[512];        // staged bias      (2 KB)
  __shared__ bf16x8 hid8[32 * 64];  // hid[32][512] bf16, swizzled (32 KB)
  float* rowdata = (float*)rowf4;
  u16* hid = (u16*)hid8;

  const uint32_t bxbf = fl[0], scbf = fl[1], w1bf = fl[2], b1bf = fl[3];
  const uint32_t b2bf = fl[5], l64 = fl[6], vbool = fl[7];
  const uint32_t outbf = fl[0];

  const int tid = threadIdx.x;
  const size_t row0 = (size_t)blockIdx.x * 32;
  const int b = (int)(row0 >> 11);

  // ---- gather: 16 threads per row ----
  {
    const int r = tid >> 4, p = tid & 15;
    int idx = idxbuf[row0 + r] & (NPTS - 1);
    size_t src = (size_t)b * NPTS + idx;
    float* rr = rowdata + r * 12;
    if (p < 4) {
      rr[2 * p] = loadf(boxes, src * 9 + 2 * p, bxbf);
      rr[2 * p + 1] = loadf(boxes, src * 9 + 2 * p + 1, bxbf);
    } else if (p == 4) {
      rr[8] = loadf(boxes, src * 9 + 8, bxbf);
      rr[9] = loadf(scores, src, scbf);
    } else if (p == 5) {
      int lab = load_label(labels, src, l64);
      lab = lab < 0 ? 0 : (lab > 22 ? 22 : lab);
      rr[10] = (float)lab;
    } else if (p == 6) {
      rr[11] = load_valid(valid, src, vbool) ? 1.0f : 0.0f;
    }
  }

  // ---- stage b2 into LDS (overlaps gather latency) ----
  b2s[tid] = loadf(b2, tid, b2bf);

  // ---- preload w1 feature columns (2 adjacent cols per thread) ----
  const int half = tid >> 8;       // 0: rows 0..15, 1: rows 16..31
  const int ct = tid & 255;
  const int c0 = 2 * ct;           // columns c0, c0+1
  float w1c0[10], w1c1[10];
#pragma unroll
  for (int f = 0; f < 10; ++f) {
    w1c0[f] = loadf(w1, f * MODEL_DIM + c0, w1bf);
    w1c1[f] = loadf(w1, f * MODEL_DIM + c0 + 1, w1bf);
  }
  const float b1c0 = loadf(b1, c0, b1bf), b1c1 = loadf(b1, c0 + 1, b1bf);
  __syncthreads();

  // ---- refs / scores outputs (fused finalize) ----
  const size_t refs0 = (size_t)NROWS * MODEL_DIM;
  const size_t scr0 = refs0 + (size_t)NROWS * 3;
  if (tid < 32) {
    const float* rr = rowdata + tid * 12;
    const float vm = rr[11];
    const size_t grow = row0 + tid;
    storef(out, refs0 + grow * 3 + 0, vm != 0.0f ? rr[0] : 0.0f, outbf);
    storef(out, refs0 + grow * 3 + 1, vm != 0.0f ? rr[1] : 0.0f, outbf);
    storef(out, refs0 + grow * 3 + 2, vm != 0.0f ? rr[2] : 0.0f, outbf);
    storef(out, scr0 + grow, vm != 0.0f ? rr[9] : 0.0f, outbf);
  }

  // ---- GEMM1: hidden = relu(features @ w1 + b1), bf16 into swizzled LDS.
  // 16 rows per half-block; one-hot w1-row loads prefetched 4 deep;
  // features read as 3x ds_read_b128 (broadcast). ----
  for (int rq = 0; rq < 16; rq += 4) {
    float oh0[4], oh1[4];
#pragma unroll
    for (int j = 0; j < 4; ++j) {
      const int r = half * 16 + rq + j;
      int lab = (int)rowdata[r * 12 + 10];
      size_t ohb = (size_t)(10 + lab) * MODEL_DIM;
      oh0[j] = loadf(w1, ohb + c0, w1bf);
      oh1[j] = loadf(w1, ohb + c0 + 1, w1bf);
    }
#pragma unroll
    for (int j = 0; j < 4; ++j) {
      const int r = half * 16 + rq + j;
      const f32x4 q0 = rowf4[r * 3 + 0];
      const f32x4 q1 = rowf4[r * 3 + 1];
      const f32x4 q2 = rowf4[r * 3 + 2];
      float h0 = b1c0 + oh0[j];
      float h1 = b1c1 + oh1[j];
      const float ft[10] = {q0[0], q0[1], q0[2], q0[3], q1[0],
                            q1[1], q1[2], q1[3], q2[0], q2[1]};
#pragma unroll
      for (int f = 0; f < 10; ++f) {
        h0 = fmaf(ft[f], w1c0[f], h0);
        h1 = fmaf(ft[f], w1c1[f], h1);
      }
      const int sw = (r & 7) << 3;  // elem XOR == byte ^= (r&7)<<4
      uint32_t pack = (uint32_t)f2bf_bits(fmaxf(h0, 0.0f)) |
                      ((uint32_t)f2bf_bits(fmaxf(h1, 0.0f)) << 16);
      *(uint32_t*)&hid[r * 512 + (c0 ^ sw)] = pack;
    }
  }
  __syncthreads();

  // ---- GEMM2: out = hidden @ w2 + b2 (bf16 MFMA, swapped operands) ----
  const int lane = tid & 63;
  const int wave = tid >> 6;       // 0..7, owns n in [wave*64, wave*64+64)
  const int quad = lane >> 4;
  const int l16 = lane & 15;
  const int kq = quad * 8;         // k-offset inside the hid fragment

  const int nbase = wave * 64;
  f32x4 acc[2][4];  // [mt][nt]
#pragma unroll
  for (int mt = 0; mt < 2; ++mt)
#pragma unroll
    for (int nt = 0; nt < 4; ++nt)
      acc[mt][nt] = f32x4{0.0f, 0.0f, 0.0f, 0.0f};

#pragma unroll 4
  for (int ks = 0; ks < 16; ++ks) {
    bf16x8 hfrag[2];
#pragma unroll
    for (int mt = 0; mt < 2; ++mt) {
      const int m = mt * 16 + l16;
      hfrag[mt] = *(const bf16x8*)&hid[m * 512 +
                                       ((ks * 32 + kq) ^ ((m & 7) << 3))];
    }
    bf16x8 wfrag[4];
#pragma unroll
    for (int nt = 0; nt < 4; ++nt) {
      // fragment-packed: chunk c = ntile*16 + ks, lane-ordered 16 B each
      const int ntile = wave * 4 + nt;
      wfrag[nt] = *(const bf16x8*)&w2f[((size_t)(ntile * 16 + ks) << 9) +
                                       (lane << 3)];
    }
#pragma unroll
    for (int nt = 0; nt < 4; ++nt)
#pragma unroll
      for (int mt = 0; mt < 2; ++mt)
        // D = A*B with A=w2 frag (free idx n), B=hid frag (free idx m):
        // D col(lane&15)=m, row(quad*4+reg)=n -> reg walks n.
        acc[mt][nt] = __builtin_amdgcn_mfma_f32_16x16x32_bf16(
            wfrag[nt], hfrag[mt], acc[mt][nt], 0, 0, 0);
  }

  // epilogue: reg walks n -> 4-wide vector stores, bias (from LDS) + mask
#pragma unroll
  for (int nt = 0; nt < 4; ++nt) {
    const int n0 = nbase + nt * 16 + quad * 4;
    const float bias0 = b2s[n0 + 0];
    const float bias1 = b2s[n0 + 1];
    const float bias2 = b2s[n0 + 2];
    const float bias3 = b2s[n0 + 3];
#pragma unroll
    for (int mt = 0; mt < 2; ++mt) {
      const int m = mt * 16 + l16;
      const float vm = rowdata[m * 12 + 11];
      f32x4 v;
      v[0] = vm != 0.0f ? acc[mt][nt][0] + bias0 : 0.0f;
      v[1] = vm != 0.0f ? acc[mt][nt][1] + bias1 : 0.0f;
      v[2] = vm != 0.0f ? acc[mt][nt][2] + bias2 : 0.0f;
      v[3] = vm != 0.0f ? acc[mt][nt][3] + bias3 : 0.0f;
      const size_t o = (row0 + m) * MODEL_DIM + n0;
      if (!outbf) {
        *(f32x4*)((float*)out + o) = v;  // 16B aligned: n0 % 4 == 0
      } else {
        ushort4 pv;
        pv.x = f2bf_bits(v[0]);
        pv.y = f2bf_bits(v[1]);
        pv.z = f2bf_bits(v[2]);
        pv.w = f2bf_bits(v[3]);
        *(ushort4*)((u16*)out + o) = pv;  // 8B aligned
      }
    }
  }
}

extern "C" void kernel_launch(void* const* d_in, const int* in_sizes, int n_in,
                              void* d_out, int out_size, void* d_ws, size_t ws_size,
                              hipStream_t stream) {
  const void* boxes  = d_in[0];
  const void* scores = d_in[1];
  const void* w1     = d_in[2];
  const void* b1     = d_in[3];
  const void* w2     = d_in[4];
  const void* b2     = d_in[5];
  const void* labels = d_in[6];
  const void* valid  = d_in[7];

  // d_ws layout: flags[16] u32 @0; w2f u16[512*512] @256; idxbuf u16 @256+512K
  uint32_t* fl = (uint32_t*)d_ws;
  u16* w2f    = (u16*)((char*)d_ws + 256);
  u16* idxbuf = (u16*)((char*)d_ws + 256 + (size_t)MODEL_DIM * MODEL_DIM * 2);

  sniff_kernel<<<1, 64, 0, stream>>>(boxes, scores, w1, b1, w2, b2, labels,
                                     valid, fl);
  w2_pack_kernel<<<dim3(16, 16), dim3(32, 8), 0, stream>>>(w2, w2f, fl);
  topk_kernel<<<BATCH, 1024, 0, stream>>>(scores, valid, idxbuf, fl);
  mlp_kernel<<<NROWS / 32, 512, 0, stream>>>(w1, b1, w2f, b2, idxbuf, boxes,
                                             scores, labels, valid, d_out, fl);
}

// Round 7
// 481.643 us; speedup vs baseline: 1.2349x; 1.2349x over previous
//
#include <hip/hip_runtime.h>
#include <stdint.h>

#define BATCH 64
#define NPTS 16384
#define MODEL_DIM 512
#define QL 2048
#define NROWS (BATCH * QL)

typedef unsigned short u16;
typedef __attribute__((ext_vector_type(8))) __bf16 bf16x8;
typedef __attribute__((ext_vector_type(4))) float f32x4;
typedef __attribute__((ext_vector_type(4))) unsigned short u16x4;  // native vec for nontemporal builtin

// flags: [0..5] bf16? for boxes,scores,w1,b1,w2,b2; [6] labels-int64?; [7] valid-bool?
// out dtype = flags[0] (reference: outputs carry object_boxes.dtype)

__device__ __forceinline__ float loadf(const void* p, size_t i, uint32_t bf) {
  if (bf) {
    uint32_t u = ((const u16*)p)[i];
    return __uint_as_float(u << 16);
  }
  return ((const float*)p)[i];
}

__device__ __forceinline__ u16 f2bf_bits(float f) {
  __bf16 h = (__bf16)f;  // RNE
  return *(const u16*)&h;
}

// non-temporal scalar store: out is write-once, never re-read -> keep it from
// evicting w2f/w1 out of L2/L3 (round-5 lesson: store stream thrashed w2f).
__device__ __forceinline__ void storef_nt(void* p, size_t i, float v,
                                          uint32_t bf) {
  if (bf) __builtin_nontemporal_store(f2bf_bits(v), (u16*)p + i);
  else    __builtin_nontemporal_store(v, (float*)p + i);
}

__device__ __forceinline__ int load_label(const void* p, size_t i, uint32_t is64) {
  return is64 ? ((const int*)p)[2 * i] : ((const int*)p)[i];  // LE low word
}

__device__ __forceinline__ int load_valid(const void* p, size_t i, uint32_t isbool) {
  return isbool ? (int)((const unsigned char*)p)[i] : ((const int*)p)[i];
}

// ---------------------------------------------------------------------------
// Kernel 0: runtime dtype sniffer -> fl[8] in d_ws. One wave, ballot-parallel.
// ---------------------------------------------------------------------------
__global__ void sniff_kernel(const void* boxes, const void* scores,
                             const void* w1, const void* b1, const void* w2,
                             const void* b2, const void* labels,
                             const void* valid, uint32_t* fl) {
  const int lane = threadIdx.x;  // 64 threads, 1 block
  const void* bufs[6] = {boxes, scores, w1, b1, w2, b2};
#pragma unroll
  for (int t = 0; t < 6; ++t) {
    u16 v = ((const u16*)bufs[t])[lane];
    uint32_t e = (v >> 7) & 0xFFu;
    unsigned long long zb = __ballot(v == 0);
    unsigned long long cb = __ballot(e >= 100u && e <= 135u);
    if (lane == 0) {
      int z = __popcll(zb), c = __popcll(cb);
      // all-zero buffer (b1/b2): read as bf16 — values are 0 either way.
      fl[t] = (z >= 60) ? 1u : (c >= 56 ? 1u : 0u);
    }
  }
  uint32_t hw = (lane < 32) ? ((const uint32_t*)labels)[2 * lane + 1] : 0u;
  unsigned long long nz = __ballot(hw != 0u);
  uint32_t vv = ((const uint32_t*)valid)[lane];
  unsigned long long big = __ballot(vv > 1u);
  if (lane == 0) {
    fl[6] = (nz == 0ull) ? 1u : 0u;  // int64 iff high words all zero
    fl[7] = big ? 1u : 0u;           // bool-packed iff any non-{0,1} word
  }
}

// ---------------------------------------------------------------------------
// Kernel 1: w2 [K][N] -> w2f, MFMA-fragment-packed bf16:
// chunk c = ntile*16 + ks  (ntile = n/16, ks = k/32), 512 elems per chunk:
//   w2f[c*512 + lane*8 + e] = w2[ks*32 + (lane>>4)*8 + e][ntile*16 + (lane&15)]
// so GEMM2's A-fragment load becomes ONE fully-coalesced 1-KB dwordx4 per
// wave (was a 16-way scattered read at 2-KB stride).
// ---------------------------------------------------------------------------
__global__ void w2_pack_kernel(const void* __restrict__ w2,
                               u16* __restrict__ w2f,
                               const uint32_t* __restrict__ fl) {
  __shared__ u16 tile[32][33];  // [k'][n']
  const uint32_t bf = fl[4];
  const int ks = blockIdx.x;  // 0..15  (k block of 32)
  const int ng = blockIdx.y;  // 0..15  (n block of 32)
  const int tx = threadIdx.x, ty = threadIdx.y;  // (32, 8)
#pragma unroll
  for (int p = 0; p < 4; ++p) {
    int k = ks * 32 + ty + p * 8;
    int n = ng * 32 + tx;
    tile[ty + p * 8][tx] = f2bf_bits(loadf(w2, (size_t)k * MODEL_DIM + n, bf));
  }
  __syncthreads();
  const int t = ty * 32 + tx;        // 0..255
  const int ch = t >> 7;             // 0/1: which 16-wide n sub-tile
  const int w = t & 127;
  const int lane = w >> 1;           // 0..63
  const int e0 = (t & 1) * 4;        // elems e0..e0+3
  const int quad = lane >> 4, l16 = lane & 15;
  const int c = (ng * 2 + ch) * 16 + ks;
  ushort4 v;
  v.x = tile[quad * 8 + e0 + 0][ch * 16 + l16];
  v.y = tile[quad * 8 + e0 + 1][ch * 16 + l16];
  v.z = tile[quad * 8 + e0 + 2][ch * 16 + l16];
  v.w = tile[quad * 8 + e0 + 3][ch * 16 + l16];
  *(ushort4*)&w2f[(size_t)c * 512 + lane * 8 + e0] = v;
}

// ---------------------------------------------------------------------------
// Kernel 2: per-batch top-2048. 64-bit key = orderable(score)<<32 | ~idx
// (distinct keys, jax-stable tie-break). One 11-bit histogram pass +
// parallel suffix-scan finds the threshold bin; candidates (bin==T, expected
// ~8) compacted to a u16 list; remaining radix passes scan only that list,
// with early exit when bucket count == r. Worst case (>4096 ties) falls back
// to full-array scans (identical semantics). Bitonic sort for final order.
// ---------------------------------------------------------------------------
__global__ __launch_bounds__(1024) void topk_kernel(
    const void* __restrict__ scores, const void* __restrict__ valid,
    u16* __restrict__ idxbuf, const uint32_t* __restrict__ fl) {
  __shared__ uint32_t sk[NPTS];   // 64 KB orderable scores
  __shared__ uint64_t sel[QL];    // 16 KB; aliased as A/B u32[2048] work areas
  __shared__ uint32_t s_cnt, s_T, s_r, s_hi, s_ccnt;

  uint32_t* Aw = (uint32_t*)sel;       // [0..2048)
  uint32_t* Bw = Aw + 2048;            // [2048..4096)
  u16* cand = (u16*)Aw;                // 4096 entries, aliases Aw (free later)

  const uint32_t sbf = fl[1], vbool = fl[7];
  const int b = blockIdx.x;
  const int tid = threadIdx.x;

  // ---- load + orderable transform ----
  for (int i = tid; i < NPTS; i += 1024) {
    size_t g = (size_t)b * NPTS + i;
    float ms = load_valid(valid, g, vbool) ? loadf(scores, g, sbf) : -1e30f;
    uint32_t u = __float_as_uint(ms);
    sk[i] = (u & 0x80000000u) ? ~u : (u | 0x80000000u);
  }
  for (int i = tid; i < 2048; i += 1024) Aw[i] = 0u;
  __syncthreads();

  // ---- 11-bit histogram over top bits ----
  for (int i = tid; i < NPTS; i += 1024) atomicAdd(&Aw[sk[i] >> 21], 1u);
  __syncthreads();

  // ---- inclusive suffix scan (Hillis-Steele, 11 steps, ends in Bw) ----
  {
    uint32_t* src = Aw;
    uint32_t* dst = Bw;
    for (int d = 1; d < 2048; d <<= 1) {
      for (int i = tid; i < 2048; i += 1024)
        dst[i] = src[i] + ((i + d < 2048) ? src[i + d] : 0u);
      __syncthreads();
      uint32_t* tp = src; src = dst; dst = tp;
    }
    // src == Bw now holds S[v] = #elements with bin >= v (11 swaps)
    for (int v = tid; v < 2048; v += 1024) {
      uint32_t Sv = src[v];
      uint32_t Sn = (v < 2047) ? src[v + 1] : 0u;
      if (Sv >= QL && Sn < QL) { s_T = (uint32_t)v; s_r = QL - Sn; s_hi = Sn; }
    }
    __syncthreads();
  }
  const uint32_t T = s_T;
  const uint32_t r0 = s_r;
  const uint32_t histT = Bw[T] - s_hi;  // candidates in threshold bin

  // ---- compact candidates (bin == T) into u16 list if they fit ----
  const bool useCand = (histT <= 4096u);
  if (tid == 0) s_ccnt = 0u;
  __syncthreads();
  if (useCand) {
    for (int i = tid; i < NPTS; i += 1024)
      if ((sk[i] >> 21) == T) {
        uint32_t p = atomicAdd(&s_ccnt, 1u);
        cand[p] = (u16)i;
      }
  }
  __syncthreads();

  // ---- refine within bin T over remaining 53 key bits ----
  uint64_t V;
  if (histT == r0) {
    V = ((uint64_t)T) << 53;  // whole bin selected
  } else {
    uint64_t P = T;
    uint32_t r = r0;
    const int pos[7] = {45, 37, 29, 21, 13, 5, 0};
    const int wid[7] = {8, 8, 8, 8, 8, 8, 5};
    int done = 0;
    V = 0;
#pragma unroll 1
    for (int pp = 0; pp < 7; ++pp) {
      if (done) break;
      const int shift = pos[pp], db = wid[pp];
      const uint32_t nb = 1u << db;
      const uint32_t mask = nb - 1u;
      for (uint32_t i = tid; i < nb; i += 1024) Bw[i] = 0u;
      __syncthreads();
      const uint64_t Pc = P;
      const int hibits = shift + db;
      if (useCand) {
        const uint32_t cc = s_ccnt;
        for (uint32_t j = tid; j < cc; j += 1024) {
          int i = cand[j];
          uint64_t k = ((uint64_t)sk[i] << 32) | (uint32_t)(~i);
          if ((k >> hibits) == Pc)
            atomicAdd(&Bw[(uint32_t)(k >> shift) & mask], 1u);
        }
      } else {
        for (int i = tid; i < NPTS; i += 1024) {
          uint64_t k = ((uint64_t)sk[i] << 32) | (uint32_t)(~i);
          if ((k >> hibits) == Pc)
            atomicAdd(&Bw[(uint32_t)(k >> shift) & mask], 1u);
        }
      }
      __syncthreads();
      // suffix scan over nb bins (ping-pong within Bw[0..2nb))
      uint32_t* s0 = Bw;
      uint32_t* s1 = Bw + nb;
      for (uint32_t d = 1; d < nb; d <<= 1) {
        for (uint32_t i = tid; i < nb; i += 1024)
          s1[i] = s0[i] + ((i + d < nb) ? s0[i + d] : 0u);
        __syncthreads();
        uint32_t* tp = s0; s0 = s1; s1 = tp;
      }
      for (uint32_t v = tid; v < nb; v += 1024) {
        uint32_t Sv = s0[v];
        uint32_t Sn = (v < nb - 1) ? s0[v + 1] : 0u;
        if (Sv >= r && Sn < r) { s_T = v; s_hi = Sn; }
      }
      __syncthreads();
      const uint32_t chosen = s_T, hi2 = s_hi;
      const uint32_t histc = s0[chosen] - hi2;
      P = (P << db) | chosen;
      r = r - hi2;
      if (histc == r || shift == 0) {
        V = P << shift;
        done = 1;
      }
      __syncthreads();  // before next pass reuses Bw / s_T
    }
  }

  // ---- selection: exactly QL keys >= V (clobbers Aw/Bw == sel) ----
  if (tid == 0) s_cnt = 0u;
  __syncthreads();
  for (int i = tid; i < NPTS; i += 1024) {
    uint64_t k = ((uint64_t)sk[i] << 32) | (uint32_t)(~i);
    if (k >= V) {
      uint32_t p = atomicAdd(&s_cnt, 1u);
      if (p < QL) sel[p] = k;
    }
  }
  __syncthreads();

  // ---- bitonic sort descending ----
  for (int kk = 2; kk <= QL; kk <<= 1) {
    for (int j = kk >> 1; j > 0; j >>= 1) {
      for (int i = tid; i < QL; i += 1024) {
        int l = i ^ j;
        if (l > i) {
          uint64_t a = sel[i], c = sel[l];
          bool dir = ((i & kk) == 0);
          if ((a < c) == dir) { sel[i] = c; sel[l] = a; }
        }
      }
      __syncthreads();
    }
  }

  for (int q = tid; q < QL; q += 1024)
    idxbuf[b * QL + q] = (u16)((~(uint32_t)sel[q]) & (NPTS - 1));
}

// ---------------------------------------------------------------------------
// Kernel 3: fused MLP. ROUND-4 geometry (the proven 209 µs regime): 64
// rows/block, 512 threads, 69 KB LDS -> 2 blocks/CU. Round-5 lesson: 32-row
// blocks doubled w2f re-read demand and 85% occupancy thrashed L2/L3
// (FETCH 42.7->263 MB, dur 209->293). Keep 64-row tile; protect w2f
// residency with NON-TEMPORAL out stores (write-once stream must not evict
// weights). b2 staged in LDS; rowdata features read as ds_read_b128.
// ---------------------------------------------------------------------------
__global__ __launch_bounds__(512, 4) void mlp_kernel(
    const void* __restrict__ w1, const void* __restrict__ b1,
    const u16* __restrict__ w2f, const void* __restrict__ b2,
    const u16* __restrict__ idxbuf, const void* __restrict__ boxes,
    const void* __restrict__ scores, const void* __restrict__ labels,
    const void* __restrict__ valid, void* __restrict__ out,
    const uint32_t* __restrict__ fl) {
  __shared__ f32x4 rowf4[192];      // rowdata[64][12]  (3 KB)
  __shared__ float b2s[512];        // staged bias      (2 KB)
  __shared__ bf16x8 hid8[64 * 64];  // hid[64][512] bf16, swizzled (64 KB)
  float* rowdata = (float*)rowf4;
  u16* hid = (u16*)hid8;

  const uint32_t bxbf = fl[0], scbf = fl[1], w1bf = fl[2], b1bf = fl[3];
  const uint32_t b2bf = fl[5], l64 = fl[6], vbool = fl[7];
  const uint32_t outbf = fl[0];

  const int tid = threadIdx.x;
  const size_t row0 = (size_t)blockIdx.x * 64;
  const int b = (int)(row0 >> 11);

  // ---- gather: 8 threads per row ----
  {
    const int r = tid >> 3, p = tid & 7;
    int idx = idxbuf[row0 + r] & (NPTS - 1);
    size_t src = (size_t)b * NPTS + idx;
    float* rr = rowdata + r * 12;
    if (p < 4) {
      rr[2 * p] = loadf(boxes, src * 9 + 2 * p, bxbf);
      rr[2 * p + 1] = loadf(boxes, src * 9 + 2 * p + 1, bxbf);
    } else if (p == 4) {
      rr[8] = loadf(boxes, src * 9 + 8, bxbf);
      rr[9] = loadf(scores, src, scbf);
    } else if (p == 5) {
      int lab = load_label(labels, src, l64);
      lab = lab < 0 ? 0 : (lab > 22 ? 22 : lab);
      rr[10] = (float)lab;
    } else if (p == 6) {
      rr[11] = load_valid(valid, src, vbool) ? 1.0f : 0.0f;
    }
  }

  // ---- stage b2 into LDS (overlaps gather latency) ----
  b2s[tid] = loadf(b2, tid, b2bf);

  // ---- preload w1 feature columns (2 adjacent cols per thread) ----
  const int half = tid >> 8;       // 0: rows 0..31, 1: rows 32..63
  const int ct = tid & 255;
  const int c0 = 2 * ct;           // columns c0, c0+1
  float w1c0[10], w1c1[10];
#pragma unroll
  for (int f = 0; f < 10; ++f) {
    w1c0[f] = loadf(w1, f * MODEL_DIM + c0, w1bf);
    w1c1[f] = loadf(w1, f * MODEL_DIM + c0 + 1, w1bf);
  }
  const float b1c0 = loadf(b1, c0, b1bf), b1c1 = loadf(b1, c0 + 1, b1bf);
  __syncthreads();

  // ---- refs / scores outputs (fused finalize, non-temporal) ----
  const size_t refs0 = (size_t)NROWS * MODEL_DIM;
  const size_t scr0 = refs0 + (size_t)NROWS * 3;
  if (tid < 64) {
    const float* rr = rowdata + tid * 12;
    const float vm = rr[11];
    const size_t grow = row0 + tid;
    storef_nt(out, refs0 + grow * 3 + 0, vm != 0.0f ? rr[0] : 0.0f, outbf);
    storef_nt(out, refs0 + grow * 3 + 1, vm != 0.0f ? rr[1] : 0.0f, outbf);
    storef_nt(out, refs0 + grow * 3 + 2, vm != 0.0f ? rr[2] : 0.0f, outbf);
    storef_nt(out, scr0 + grow, vm != 0.0f ? rr[9] : 0.0f, outbf);
  }

  // ---- GEMM1: hidden = relu(features @ w1 + b1), bf16 into swizzled LDS.
  // 32 rows per half-block; one-hot w1-row loads prefetched 4 deep;
  // features read as 3x ds_read_b128 (broadcast). ----
  for (int rq = 0; rq < 32; rq += 4) {
    float oh0[4], oh1[4];
#pragma unroll
    for (int j = 0; j < 4; ++j) {
      const int r = half * 32 + rq + j;
      int lab = (int)rowdata[r * 12 + 10];
      size_t ohb = (size_t)(10 + lab) * MODEL_DIM;
      oh0[j] = loadf(w1, ohb + c0, w1bf);
      oh1[j] = loadf(w1, ohb + c0 + 1, w1bf);
    }
#pragma unroll
    for (int j = 0; j < 4; ++j) {
      const int r = half * 32 + rq + j;
      const f32x4 q0 = rowf4[r * 3 + 0];
      const f32x4 q1 = rowf4[r * 3 + 1];
      const f32x4 q2 = rowf4[r * 3 + 2];
      float h0 = b1c0 + oh0[j];
      float h1 = b1c1 + oh1[j];
      const float ft[10] = {q0[0], q0[1], q0[2], q0[3], q1[0],
                            q1[1], q1[2], q1[3], q2[0], q2[1]};
#pragma unroll
      for (int f = 0; f < 10; ++f) {
        h0 = fmaf(ft[f], w1c0[f], h0);
        h1 = fmaf(ft[f], w1c1[f], h1);
      }
      const int sw = (r & 7) << 3;  // elem XOR == byte ^= (r&7)<<4
      uint32_t pack = (uint32_t)f2bf_bits(fmaxf(h0, 0.0f)) |
                      ((uint32_t)f2bf_bits(fmaxf(h1, 0.0f)) << 16);
      *(uint32_t*)&hid[r * 512 + (c0 ^ sw)] = pack;
    }
  }
  __syncthreads();

  // ---- GEMM2: out = hidden @ w2 + b2 (bf16 MFMA, swapped operands) ----
  const int lane = tid & 63;
  const int wave = tid >> 6;       // 0..7, owns n in [wave*64, wave*64+64)
  const int quad = lane >> 4;
  const int l16 = lane & 15;
  const int kq = quad * 8;         // k-offset inside the hid fragment

  const int nbase = wave * 64;
  f32x4 acc[4][4];  // [mt][nt]
#pragma unroll
  for (int mt = 0; mt < 4; ++mt)
#pragma unroll
    for (int nt = 0; nt < 4; ++nt)
      acc[mt][nt] = f32x4{0.0f, 0.0f, 0.0f, 0.0f};

#pragma unroll 4
  for (int ks = 0; ks < 16; ++ks) {
    bf16x8 hfrag[4];
#pragma unroll
    for (int mt = 0; mt < 4; ++mt) {
      const int m = mt * 16 + l16;
      hfrag[mt] = *(const bf16x8*)&hid[m * 512 +
                                       ((ks * 32 + kq) ^ ((m & 7) << 3))];
    }
    bf16x8 wfrag[4];
#pragma unroll
    for (int nt = 0; nt < 4; ++nt) {
      // fragment-packed: chunk c = ntile*16 + ks, lane-ordered 16 B each
      const int ntile = wave * 4 + nt;
      wfrag[nt] = *(const bf16x8*)&w2f[((size_t)(ntile * 16 + ks) << 9) +
                                       (lane << 3)];
    }
#pragma unroll
    for (int nt = 0; nt < 4; ++nt)
#pragma unroll
      for (int mt = 0; mt < 4; ++mt)
        // D = A*B with A=w2 frag (free idx n), B=hid frag (free idx m):
        // D col(lane&15)=m, row(quad*4+reg)=n -> reg walks n.
        acc[mt][nt] = __builtin_amdgcn_mfma_f32_16x16x32_bf16(
            wfrag[nt], hfrag[mt], acc[mt][nt], 0, 0, 0);
  }

  // epilogue: reg walks n -> 4-wide NON-TEMPORAL stores, bias (LDS) + mask
#pragma unroll
  for (int nt = 0; nt < 4; ++nt) {
    const int n0 = nbase + nt * 16 + quad * 4;
    const float bias0 = b2s[n0 + 0];
    const float bias1 = b2s[n0 + 1];
    const float bias2 = b2s[n0 + 2];
    const float bias3 = b2s[n0 + 3];
#pragma unroll
    for (int mt = 0; mt < 4; ++mt) {
      const int m = mt * 16 + l16;
      const float vm = rowdata[m * 12 + 11];
      f32x4 v;
      v[0] = vm != 0.0f ? acc[mt][nt][0] + bias0 : 0.0f;
      v[1] = vm != 0.0f ? acc[mt][nt][1] + bias1 : 0.0f;
      v[2] = vm != 0.0f ? acc[mt][nt][2] + bias2 : 0.0f;
      v[3] = vm != 0.0f ? acc[mt][nt][3] + bias3 : 0.0f;
      const size_t o = (row0 + m) * MODEL_DIM + n0;
      if (!outbf) {
        __builtin_nontemporal_store(v, (f32x4*)((float*)out + o));
      } else {
        u16x4 pv;
        pv[0] = f2bf_bits(v[0]);
        pv[1] = f2bf_bits(v[1]);
        pv[2] = f2bf_bits(v[2]);
        pv[3] = f2bf_bits(v[3]);
        __builtin_nontemporal_store(pv, (u16x4*)((u16*)out + o));
      }
    }
  }
}

extern "C" void kernel_launch(void* const* d_in, const int* in_sizes, int n_in,
                              void* d_out, int out_size, void* d_ws, size_t ws_size,
                              hipStream_t stream) {
  const void* boxes  = d_in[0];
  const void* scores = d_in[1];
  const void* w1     = d_in[2];
  const void* b1     = d_in[3];
  const void* w2     = d_in[4];
  const void* b2     = d_in[5];
  const void* labels = d_in[6];
  const void* valid  = d_in[7];

  // d_ws layout: flags[16] u32 @0; w2f u16[512*512] @256; idxbuf u16 @256+512K
  uint32_t* fl = (uint32_t*)d_ws;
  u16* w2f    = (u16*)((char*)d_ws + 256);
  u16* idxbuf = (u16*)((char*)d_ws + 256 + (size_t)MODEL_DIM * MODEL_DIM * 2);

  sniff_kernel<<<1, 64, 0, stream>>>(boxes, scores, w1, b1, w2, b2, labels,
                                     valid, fl);
  w2_pack_kernel<<<dim3(16, 16), dim3(32, 8), 0, stream>>>(w2, w2f, fl);
  topk_kernel<<<BATCH, 1024, 0, stream>>>(scores, valid, idxbuf, fl);
  mlp_kernel<<<NROWS / 64, 512, 0, stream>>>(w1, b1, w2f, b2, idxbuf, boxes,
                                             scores, labels, valid, d_out, fl);
}